// Round 5
// baseline (300.819 us; speedup 1.0000x reference)
//
#include <hip/hip_runtime.h>

#define NPTS 65536
#define MM_BLOCKS 64

// packed-weight layout inside d_ws (float offsets, all float4-aligned)
#define WT_OFF   128   // packed weights start here (after minmax partials)
#define OFF_L1   0     // W1T[j*3+i] (9) + b1 (3)            -> 12 (pad 16)
#define OFF_L2   16    // + 20*r : { w[jj*3+ii] (15), b[jj] (5) }   -> ends 96
#define OFF_MID  96    // + 480*l + 120*r : { o=0..3: w25 @28*o (w[jj*5+ii]) ; b5 @112 }
#define OFF_L8   2496  // + 40*r (r in 0..1) : { o=0..3: w5 @8*o ; b @32 }
#define PK_TOTAL 2576

// ---------------------------------------------------------------------------
// fast tanh: tanh(x) = 1 - 2/(e^{2x}+1).
// ---------------------------------------------------------------------------
__device__ __forceinline__ float fast_tanh(float x) {
  float e = __expf(2.0f * x);
  float r = __builtin_amdgcn_rcpf(e + 1.0f);
  return fmaf(-2.0f, r, 1.0f);
}

// quad cross-lane: rotate (lane r <- lane (r+1)&3) and broadcast quad lane 1.
// DPP quad_perm: full-rate VALU, no LDS pipe, wave-synchronous.
__device__ __forceinline__ float qrot(float x) {
  int i = __float_as_int(x);
  i = __builtin_amdgcn_update_dpp(i, i, 0x39 /*quad_perm [1,2,3,0]*/, 0xF, 0xF, false);
  return __int_as_float(i);
}
__device__ __forceinline__ float qbcast1(float x) {
  int i = __float_as_int(x);
  i = __builtin_amdgcn_update_dpp(i, i, 0x55 /*quad_perm [1,1,1,1]*/, 0xF, 0xF, false);
  return __int_as_float(i);
}

// ---------------------------------------------------------------------------
// Univariate order-3 jet.
// ---------------------------------------------------------------------------
struct J3 {
  float v, c1, c2, c3;
  __device__ __forceinline__ static J3 seed(float bias) {
    J3 z; z.v = bias; z.c1 = 0.f; z.c2 = 0.f; z.c3 = 0.f; return z;
  }
  __device__ __forceinline__ void macc(float w, const J3& o) {
    v  = fmaf(w, o.v,  v);
    c1 = fmaf(w, o.c1, c1);
    c2 = fmaf(w, o.c2, c2);
    c3 = fmaf(w, o.c3, c3);
  }
  __device__ __forceinline__ J3 chain() const {
    float s    = fast_tanh(v);
    float fp   = fmaf(-s, s, 1.0f);
    float fpp  = -2.0f * s * fp;
    float fppp = fmaf(6.0f * s, s, -2.0f) * fp;
    J3 r;
    r.v  = s;
    r.c1 = fp * c1;
    r.c2 = fmaf(fpp, c1 * c1, fp * c2);
    r.c3 = fmaf(fppp * c1, c1 * c1, fmaf(3.0f * fpp, c1 * c2, fp * c3));
    return r;
  }
  __device__ __forceinline__ static J3 rot(const J3& o) {
    J3 x; x.v = qrot(o.v); x.c1 = qrot(o.c1); x.c2 = qrot(o.c2); x.c3 = qrot(o.c3);
    return x;
  }
};

// ---------------------------------------------------------------------------
// Mixed second-order jet.
// ---------------------------------------------------------------------------
struct JM {
  float v, a, b, m;
  __device__ __forceinline__ static JM seed(float bias) {
    JM z; z.v = bias; z.a = 0.f; z.b = 0.f; z.m = 0.f; return z;
  }
  __device__ __forceinline__ void macc(float w, const JM& o) {
    v = fmaf(w, o.v, v);
    a = fmaf(w, o.a, a);
    b = fmaf(w, o.b, b);
    m = fmaf(w, o.m, m);
  }
  __device__ __forceinline__ JM chain() const {
    float s   = fast_tanh(v);
    float fp  = fmaf(-s, s, 1.0f);
    float fpp = -2.0f * s * fp;
    JM r;
    r.v = s;
    r.a = fp * a;
    r.b = fp * b;
    r.m = fmaf(fpp, a * b, fp * m);
    return r;
  }
  __device__ __forceinline__ static JM rot(const JM& o) {
    JM x; x.v = qrot(o.v); x.a = qrot(o.a); x.b = qrot(o.b); x.m = qrot(o.m);
    return x;
  }
};

// ---------------------------------------------------------------------------
// Quad-distributed network. Lane r of each aligned quad owns output neurons
// {5r..5r+4} of every 20-wide layer; the 20 inputs circulate via qrot.
// Returns the lane's owned final-layer jet: lane0 -> psi, lane1 -> p
// (lanes 2,3 compute discarded values but carry H data for the rotations).
// ---------------------------------------------------------------------------
template <class J>
__device__ __forceinline__ J quad_net(const float* __restrict__ lds, int r,
                                      const J in3[3]) {
  // L1 (3->3): replicated on all lanes
  J T[3];
#pragma unroll
  for (int j = 0; j < 3; ++j) {
    J z = J::seed(lds[OFF_L1 + 9 + j]);
#pragma unroll
    for (int i = 0; i < 3; ++i) z.macc(lds[OFF_L1 + j * 3 + i], in3[i]);
    T[j] = z.chain();
  }
  // L2 (3->20): own 5
  const float* w2 = lds + OFF_L2 + 20 * r;
  J H[5];
#pragma unroll
  for (int jj = 0; jj < 5; ++jj) {
    J z = J::seed(w2[15 + jj]);
#pragma unroll
    for (int i = 0; i < 3; ++i) z.macc(w2[jj * 3 + i], T[i]);
    H[jj] = z.chain();
  }
  // mids (20->20) x5
#pragma unroll 1
  for (int l = 0; l < 5; ++l) {
    const float* wr = lds + OFF_MID + 480 * l + 120 * r;
    J z[5];
#pragma unroll
    for (int jj = 0; jj < 5; ++jj) z[jj] = J::seed(wr[112 + jj]);
#pragma unroll
    for (int s = 0; s < 4; ++s) {
      const float* wc = wr + 28 * ((r + s) & 3);  // chunk for H's current owner
#pragma unroll
      for (int jj = 0; jj < 5; ++jj)
#pragma unroll
        for (int ii = 0; ii < 5; ++ii)
          z[jj].macc(wc[jj * 5 + ii], H[ii]);
      if (s < 3) {
#pragma unroll
        for (int ii = 0; ii < 5; ++ii) H[ii] = J::rot(H[ii]);
      }
    }
#pragma unroll
    for (int jj = 0; jj < 5; ++jj) H[jj] = z[jj].chain();
  }
  // L8 (20->2): lane0 psi, lane1 p; lanes 2,3 read r&1 weights (discarded)
  const float* w8 = lds + OFF_L8 + 40 * (r & 1);
  J z = J::seed(w8[32]);
#pragma unroll
  for (int s = 0; s < 4; ++s) {
    const float* wc = w8 + 8 * ((r + s) & 3);
#pragma unroll
    for (int ii = 0; ii < 5; ++ii) z.macc(wc[ii], H[ii]);
    if (s < 3) {
#pragma unroll
      for (int ii = 0; ii < 5; ++ii) H[ii] = J::rot(H[ii]);
    }
  }
  return z.chain();
}

// ---------------------------------------------------------------------------
// min/max helpers
// ---------------------------------------------------------------------------
__device__ __forceinline__ unsigned flipk(float f) {
  unsigned u = __float_as_uint(f);
  return (u & 0x80000000u) ? ~u : (u | 0x80000000u);
}
__device__ __forceinline__ float unflip(unsigned k) {
  unsigned u = (k & 0x80000000u) ? (k ^ 0x80000000u) : ~k;
  return __uint_as_float(u);
}

// ---------------------------------------------------------------------------
// prep: 64 blocks of minmax partials; block 0 also packs weights into ws.
// ---------------------------------------------------------------------------
__global__ void __launch_bounds__(256) prep(
    const float* __restrict__ X, unsigned* __restrict__ part,
    float* __restrict__ wt,
    const float* W1, const float* b1, const float* W2, const float* b2,
    const float* W3, const float* b3, const float* W4, const float* b4,
    const float* W5, const float* b5, const float* W6, const float* b6,
    const float* W7, const float* b7, const float* W8, const float* b8) {
  __shared__ unsigned smin[4], smax[4];
  unsigned kmin = 0xFFFFFFFFu, kmax = 0u;
  for (int i = blockIdx.x * 256 + threadIdx.x; i < NPTS; i += MM_BLOCKS * 256) {
    unsigned key = flipk(X[3 * i]);
    kmin = min(kmin, key);
    kmax = max(kmax, key);
  }
#pragma unroll
  for (int o = 32; o > 0; o >>= 1) {
    kmin = min(kmin, (unsigned)__shfl_down((int)kmin, o, 64));
    kmax = max(kmax, (unsigned)__shfl_down((int)kmax, o, 64));
  }
  int wave = threadIdx.x >> 6;
  if ((threadIdx.x & 63) == 0) { smin[wave] = kmin; smax[wave] = kmax; }
  __syncthreads();
  if (threadIdx.x == 0) {
    part[2 * blockIdx.x]     = min(min(smin[0], smin[1]), min(smin[2], smin[3]));
    part[2 * blockIdx.x + 1] = max(max(smax[0], smax[1]), max(smax[2], smax[3]));
  }

  if (blockIdx.x == 0) {
    const int t = threadIdx.x;
    const float* Wm[5] = {W3, W4, W5, W6, W7};
    const float* bm[5] = {b3, b4, b5, b6, b7};
    if (t < 80) {                       // mid weights: (l, r, o) chunk
      int l = t / 16, rem = t % 16, r = rem / 4, o = rem % 4;
      float* dst = wt + OFF_MID + 480 * l + 120 * r + 28 * o;
      const float* Wsrc = Wm[l];
      for (int jj = 0; jj < 5; ++jj)
        for (int ii = 0; ii < 5; ++ii)
          dst[jj * 5 + ii] = Wsrc[(5 * o + ii) * 20 + (5 * r + jj)];
    } else if (t < 100) {               // mid biases
      int q = t - 80, l = q / 4, r = q % 4;
      float* dst = wt + OFF_MID + 480 * l + 120 * r + 112;
      for (int jj = 0; jj < 5; ++jj) dst[jj] = bm[l][5 * r + jj];
    } else if (t < 102) {               // L8
      int r = t - 100;
      float* dst = wt + OFF_L8 + 40 * r;
      for (int o = 0; o < 4; ++o)
        for (int ii = 0; ii < 5; ++ii)
          dst[8 * o + ii] = W8[(5 * o + ii) * 2 + r];
      dst[32] = b8[r];
    } else if (t < 106) {               // L2
      int r = t - 102;
      float* dst = wt + OFF_L2 + 20 * r;
      for (int jj = 0; jj < 5; ++jj) {
        for (int i = 0; i < 3; ++i) dst[jj * 3 + i] = W2[i * 20 + 5 * r + jj];
        dst[15 + jj] = b2[5 * r + jj];
      }
    } else if (t == 106) {              // L1
      float* dst = wt + OFF_L1;
      for (int j = 0; j < 3; ++j) {
        for (int i = 0; i < 3; ++i) dst[j * 3 + i] = W1[i * 3 + j];
        dst[9 + j] = b1[j];
      }
    }
  }
}

// ---------------------------------------------------------------------------
// main: 4 lanes per point (quad split). 1024 blocks x 256 thr = 4096 waves
// = 4 waves/SIMD, admissible because VGPR <= 128 (40-float hot state/lane).
// ---------------------------------------------------------------------------
__global__ void __launch_bounds__(256) pinn_main(
    const float* __restrict__ X, const float* __restrict__ wt,
    const unsigned* __restrict__ part,
    const float* __restrict__ lam1p, const float* __restrict__ lam2p,
    float* __restrict__ out) {
  __shared__ __align__(16) float lds[PK_TOTAL];
  for (int s = threadIdx.x; s < PK_TOTAL; s += 256) lds[s] = wt[s];
  __syncthreads();

  unsigned kminu = 0xFFFFFFFFu, kmaxu = 0u;
#pragma unroll 8
  for (int i = 0; i < MM_BLOCKS; ++i) {
    kminu = min(kminu, part[2 * i]);
    kmaxu = max(kmaxu, part[2 * i + 1]);
  }
  float lb = unflip(kminu), ub = unflip(kmaxu);
  float kk = 2.0f / (ub - lb);
  float lam1 = lam1p[0], lam2 = lam2p[0];

  const int tid = threadIdx.x;
  const int r = tid & 3;
  const int gid = (blockIdx.x * 256 + tid) >> 2;

  float x = X[3 * gid], y = X[3 * gid + 1], tt = X[3 * gid + 2];
  float h0 = fmaf(kk, x - lb, -1.0f);
  float h1 = fmaf(kk, y - lb, -1.0f);
  float h2 = fmaf(kk, tt - lb, -1.0f);

  // J3 passes PX(kk,0) PY(0,kk) PP(kk,kk) PM(kk,-kk); named scalar saves
  // (no dynamically-indexed arrays -> no scratch).
  float px_v = 0, px_c1 = 0, px_c2 = 0, px_c3 = 0;
  float py_c1 = 0, py_c2 = 0, py_c3 = 0;
  float S2p = 0, S3p = 0, S2m = 0, S3m = 0;
#pragma unroll 1
  for (int ph = 0; ph < 4; ++ph) {
    float dx = (ph == 1) ? 0.0f : kk;
    float dy = (ph == 0) ? 0.0f : ((ph == 3) ? -kk : kk);
    J3 in3[3];
    in3[0].v = h0; in3[0].c1 = dx;  in3[0].c2 = 0.f; in3[0].c3 = 0.f;
    in3[1].v = h1; in3[1].c1 = dy;  in3[1].c2 = 0.f; in3[1].c3 = 0.f;
    in3[2].v = h2; in3[2].c1 = 0.f; in3[2].c2 = 0.f; in3[2].c3 = 0.f;
    J3 O = quad_net<J3>(lds, r, in3);
    if (ph == 0)      { px_v = O.v; px_c1 = O.c1; px_c2 = O.c2; px_c3 = O.c3; }
    else if (ph == 1) { py_c1 = O.c1; py_c2 = O.c2; py_c3 = O.c3; }
    else if (ph == 2) { S2p = O.c2; S3p = O.c3; }
    else              { S2m = O.c2; S3m = O.c3; }
  }

  // JM passes XT, YT
  float mxt = 0, myt = 0;
#pragma unroll 1
  for (int ph = 0; ph < 2; ++ph) {
    JM in3[3];
    in3[0].v = h0; in3[0].a = ph ? 0.0f : kk; in3[0].b = 0.f; in3[0].m = 0.f;
    in3[1].v = h1; in3[1].a = ph ? kk : 0.0f; in3[1].b = 0.f; in3[1].m = 0.f;
    in3[2].v = h2; in3[2].a = 0.f;            in3[2].b = kk;  in3[2].m = 0.f;
    JM O = quad_net<JM>(lds, r, in3);
    if (ph == 0) mxt = O.m; else myt = O.m;
  }

  // pull p results from quad lane 1 to all lanes (before any divergence)
  float p_val = qbcast1(px_v);
  float p_x   = qbcast1(px_c1);
  float p_y   = qbcast1(py_c1);

  if (r == 0) {
    float psi_x = px_c1, psi_xx = px_c2, psi_xxx = px_c3;
    float psi_y = py_c1, psi_yy = py_c2, psi_yyy = py_c3;
    float psi_xt = mxt, psi_yt = myt;

    // polarization identities
    float psi_xy  = 0.25f * (S2p - S2m);
    float psi_xxy = (S3p - S3m - 2.0f * psi_yyy) * (1.0f / 6.0f);
    float psi_xyy = (S3p + S3m - 2.0f * psi_xxx) * (1.0f / 6.0f);

    float u = psi_y, vv = -psi_x;
    float u_x = psi_xy,  u_y = psi_yy,  u_t = psi_yt;
    float v_x = -psi_xx, v_y = -psi_xy, v_t = -psi_xt;
    float u_xx = psi_xxy,  u_yy = psi_yyy;
    float v_xx = -psi_xxx, v_yy = -psi_xyy;

    float f_u = u_t + lam1 * (u * u_x + vv * u_y) + p_x - lam2 * (u_xx + u_yy);
    float f_v = v_t + lam1 * (u * v_x + vv * v_y) + p_y - lam2 * (v_xx + v_yy);

    out[gid] = u;
    out[NPTS + gid] = vv;
    out[2 * NPTS + gid] = p_val;
    out[3 * NPTS + gid] = f_u;
    out[4 * NPTS + gid] = f_v;
  }
}

extern "C" void kernel_launch(void* const* d_in, const int* in_sizes, int n_in,
                              void* d_out, int out_size, void* d_ws, size_t ws_size,
                              hipStream_t stream) {
  (void)in_sizes; (void)n_in; (void)out_size; (void)ws_size;
  const float* X = (const float*)d_in[0];
  const float* W[8]; const float* B[8];
  for (int i = 0; i < 8; ++i) {
    W[i] = (const float*)d_in[1 + 2 * i];
    B[i] = (const float*)d_in[2 + 2 * i];
  }
  const float* lam1 = (const float*)d_in[17];
  const float* lam2 = (const float*)d_in[18];
  unsigned* part = (unsigned*)d_ws;
  float* wt = (float*)d_ws + WT_OFF;
  float* out = (float*)d_out;

  hipLaunchKernelGGL(prep, dim3(MM_BLOCKS), dim3(256), 0, stream,
                     X, part, wt,
                     W[0], B[0], W[1], B[1], W[2], B[2], W[3], B[3],
                     W[4], B[4], W[5], B[5], W[6], B[6], W[7], B[7]);
  hipLaunchKernelGGL(pinn_main, dim3(NPTS * 4 / 256), dim3(256), 0, stream,
                     X, wt, part, lam1, lam2, out);
}